// Round 2
// baseline (341.823 us; speedup 1.0000x reference)
//
#include <hip/hip_runtime.h>

#define ORDER 24
#define W 25                      // row width = ORDER + 1
#define CHUNK_ROWS 256            // rows per chunk (one LDS buffer)
#define THREADS 256
#define WAVE_FLOATS (64 * W)      // 1600 floats = 6400 B per wave per chunk

// Levinson recursion: PARCOR (reflection) -> LPC coefficients, one thread/row.
// a[m] is unmodified before step m, so k[m] == a[m] on entry to step m.
__device__ __forceinline__ void levinson(float* __restrict__ a)
{
    #pragma unroll
    for (int m = 2; m <= ORDER; ++m) {
        const float km = a[m];
        #pragma unroll
        for (int j = 1; j <= (m - 1) / 2; ++j) {
            const float lo = a[j], hi = a[m - j];
            a[j]     = fmaf(km, hi, lo);
            a[m - j] = fmaf(km, lo, hi);
        }
        if ((m & 1) == 0) {              // self-paired middle element
            const float v = a[m / 2];
            a[m / 2] = fmaf(km, v, v);
        }
    }
}

// HBM -> LDS DMA of one wave's 6400-B slice: 6x1024B (width 16) + 1x256B (width 4).
// LDS dest is wave-uniform base + lane*width (the DMA's hard constraint);
// layout is linear so this matches exactly.
__device__ __forceinline__ void dma_wave_slice(const float* __restrict__ g,
                                               float* __restrict__ l, int lane)
{
    #pragma unroll
    for (int k = 0; k < 6; ++k)
        __builtin_amdgcn_global_load_lds(
            (const __attribute__((address_space(1))) void*)(g + k * 256 + lane * 4),
            (__attribute__((address_space(3))) void*)(l + k * 256), 16, 0, 0);
    __builtin_amdgcn_global_load_lds(
        (const __attribute__((address_space(1))) void*)(g + 1536 + lane),
        (__attribute__((address_space(3))) void*)(l + 1536), 4, 0, 0);
}

// 2-chunk pipelined, wave-autonomous streaming version:
//  - each block owns two consecutive 256-row chunks, double-buffered in LDS
//  - each wave64 owns 64 rows = 6400 B of contiguous LDS per buffer (wave-private)
//  - both chunks' DMAs issue up front (12.8 KB in flight/wave); chunk1's HBM
//    latency hides under chunk0's compute -> no idle-wait phase
//  - vmcnt(7) = "chunk0's 7 DMAs done"; vmcnt(0) placed BEFORE chunk0's
//    stage-out stores so it only ever waits on chunk1's loads (robust against
//    however many store instructions the compiler emits)
//  - NO __syncthreads anywhere on the fast path
__global__ __launch_bounds__(THREADS)
void parcor2lpc_kernel(const float* __restrict__ in,
                       float* __restrict__ out, int rows)
{
    __shared__ __align__(16) float lds[2][CHUNK_ROWS * W];   // 51.2 KB -> 3 blocks/CU

    const int t    = threadIdx.x;
    const int wave = t >> 6;
    const int lane = t & 63;

    const long long c0    = (long long)blockIdx.x * 2;       // first chunk id
    const long long row00 = c0 * CHUNK_ROWS;
    const long long rem0  = (long long)rows - row00;

    if (rem0 >= 2 * CHUNK_ROWS) {
        // ---------------- fast path: barrier-free, pipelined ----------------
        const int wb = wave * WAVE_FLOATS;                   // wave-uniform
        const float* g0 = in + row00 * W + wb;
        const float* g1 = g0 + CHUNK_ROWS * W;

        dma_wave_slice(g0, &lds[0][wb], lane);               // 7 VMEM
        dma_wave_slice(g1, &lds[1][wb], lane);               // 7 VMEM

        asm volatile("s_waitcnt vmcnt(7)" ::: "memory");     // chunk0 slice ready

        // ---- chunk 0 compute + LDS writeback ----
        {
            float a[W];
            #pragma unroll
            for (int j = 0; j < W; ++j) a[j] = lds[0][t * W + j];
            levinson(a);
            #pragma unroll
            for (int j = 0; j < W; ++j) lds[0][t * W + j] = a[j];
        }

        // chunk1's 7 loads are the ONLY VMEM still outstanding; they've had
        // chunk0's whole compute (~900 cy) to land, so this rarely stalls.
        asm volatile("s_waitcnt vmcnt(0)" ::: "memory");     // chunk1 slice ready

        // ---- chunk0 stage-out + chunk1 compute/stage-out (freely scheduled) ----
        {
            float4* __restrict__ gout = (float4*)(out + row00 * W);
            const float4* sv = (const float4*)&lds[0][0];
            const int f0 = wave * (WAVE_FLOATS / 4);         // 400 float4 / wave
            #pragma unroll
            for (int k = 0; k < 6; ++k)
                gout[f0 + k * 64 + lane] = sv[f0 + k * 64 + lane];
            if (lane < 16)
                gout[f0 + 384 + lane] = sv[f0 + 384 + lane];
        }
        {
            float a[W];
            #pragma unroll
            for (int j = 0; j < W; ++j) a[j] = lds[1][t * W + j];
            levinson(a);
            #pragma unroll
            for (int j = 0; j < W; ++j) lds[1][t * W + j] = a[j];

            float4* __restrict__ gout = (float4*)(out + (row00 + CHUNK_ROWS) * W);
            const float4* sv = (const float4*)&lds[1][0];
            const int f0 = wave * (WAVE_FLOATS / 4);
            #pragma unroll
            for (int k = 0; k < 6; ++k)
                gout[f0 + k * 64 + lane] = sv[f0 + k * 64 + lane];
            if (lane < 16)
                gout[f0 + 384 + lane] = sv[f0 + 384 + lane];
        }
    } else {
        // ---------------- generic tail path (not hit at benched size) ----------------
        for (int c = 0; c < 2; ++c) {
            const long long row0 = (c0 + c) * CHUNK_ROWS;
            const long long rem  = (long long)rows - row0;
            if (rem <= 0) break;
            const int nrows = rem >= CHUNK_ROWS ? CHUNK_ROWS : (int)rem;
            const long long base = row0 * W;
            float* buf = lds[c];
            for (int i = t; i < nrows * W; i += THREADS)
                buf[i] = in[base + i];
            __syncthreads();
            if (t < nrows) {
                float a[W];
                for (int j = 0; j < W; ++j) a[j] = buf[t * W + j];
                levinson(a);
                for (int j = 0; j < W; ++j) buf[t * W + j] = a[j];
            }
            __syncthreads();
            for (int i = t; i < nrows * W; i += THREADS)
                out[base + i] = buf[i];
            __syncthreads();
        }
    }
}

extern "C" void kernel_launch(void* const* d_in, const int* in_sizes, int n_in,
                              void* d_out, int out_size, void* d_ws, size_t ws_size,
                              hipStream_t stream) {
    const float* k = (const float*)d_in[0];
    float* out = (float*)d_out;
    const int rows = in_sizes[0] / W;                        // 2,097,152
    const int chunks = (rows + CHUNK_ROWS - 1) / CHUNK_ROWS; // 8192
    const int grid = (chunks + 1) / 2;                       // 4096
    parcor2lpc_kernel<<<grid, THREADS, 0, stream>>>(k, out, rows);
}